// Round 19
// baseline (194.609 us; speedup 1.0000x reference)
//
#include <hip/hip_runtime.h>

// MultiHeadRouter: B=2, L=4096, H=16, S=64, D=128
// out (float32): [T*H ones][T*H argmax-as-float][1 loss], T = 8192
//
// R19 = R18 router core (absmax 0 x3) compressed to TWO dispatches:
// - prep_w: W->f16 hi/lo fragment planes + rep zero + ones-plane fill +
//   loss-counter zero (all coalesced).
// - router: R15/R18 core verbatim; idx written DIRECTLY to out (scattered
//   owner-lane dwords, fire-and-forget; same-line writes merge in L2);
//   loss via last-block-done (R8-verified fence/counter pattern).
// No finale dispatch, no idx_scr round-trip.

#define TOKENS  8192
#define NHEAD   16
#define NSTATE  64
#define DDIM    128
#define TH      (TOKENS * NHEAD)
#define NBLK    1024

// d_ws layout
#define WFRAG_BYTES (1u << 19)                 // 512 KB fragment planes
#define REP_OFF     WFRAG_BYTES                // 64 KB: repf[8][1024], repc[8][1024]
#define CNT_OFF     (REP_OFF + 65536)          // 4 B loss counter

typedef _Float16 half8 __attribute__((ext_vector_type(8)));
typedef float    f32x4 __attribute__((ext_vector_type(4)));

#define GLOAD_LDS16(gsrc, ldst)                                           \
    __builtin_amdgcn_global_load_lds(                                     \
        (const __attribute__((address_space(1))) void*)(gsrc),            \
        (__attribute__((address_space(3))) void*)(ldst), 16, 0, 0)

__device__ __forceinline__ unsigned int ordf(float f) {
    unsigned int u = __float_as_uint(f);
    return (u & 0x80000000u) ? ~u : (u | 0x80000000u);   // order-preserving
}

__device__ __forceinline__ void split8(const f32x4 v0, const f32x4 v1,
                                       half8& hh, half8& ll) {
    #pragma unroll
    for (int j = 0; j < 4; ++j) {
        _Float16 h0 = (_Float16)v0[j];
        hh[j]     = h0;  ll[j]     = (_Float16)(v0[j] - (float)h0);
        _Float16 h1 = (_Float16)v1[j];
        hh[4 + j] = h1;  ll[4 + j] = (_Float16)(v1[j] - (float)h1);
    }
}

// One-shot: W -> fragment-ordered f16 hi/lo planes (R7-verified layout),
// zero replicas + counter, fill the ones output plane.
__global__ __launch_bounds__(256)
void prep_w(const float* __restrict__ w, half8* __restrict__ wfrag,
            float* __restrict__ rep, int* __restrict__ counter,
            float* __restrict__ out)
{
    const int t    = blockIdx.x * 256 + threadIdx.x;   // 16384 threads
    rep[t] = 0.0f;
    if (t == 0) *counter = 0;

    // ones plane: 131072 floats, 8 per thread, contiguous
    {
        const f32x4 one4 = {1.f, 1.f, 1.f, 1.f};
        f32x4* op = reinterpret_cast<f32x4*>(out) + (size_t)t * 2;
        op[0] = one4; op[1] = one4;
    }

    const int lane = t & 63;
    const int n    = (t >> 6) & 3;
    const int ks   = (t >> 8) & 3;
    const int h    = t >> 10;
    const int s    = n * 16 + (lane & 15);
    const int k0   = ks * 32 + (lane >> 4) * 8;
    const float* src = w + (size_t)(h * NSTATE + s) * DDIM + k0;
    f32x4 v0 = *reinterpret_cast<const f32x4*>(src);
    f32x4 v1 = *reinterpret_cast<const f32x4*>(src + 4);
    half8 hv, lv;
    split8(v0, v1, hv, lv);
    const size_t hb = (size_t)h * 2048;
    const int fb = (ks * 4 + n) * 2;
    wfrag[hb + (size_t)fb * 64 + lane]       = hv;
    wfrag[hb + (size_t)(fb + 1) * 64 + lane] = lv;
}

__global__ __launch_bounds__(512)
void router_mfma(const float* __restrict__ x,      // [T,H,D]
                 const half8* __restrict__ wfrag,  // fragment planes
                 const float* __restrict__ bias,   // [H,S]
                 float* __restrict__ out,          // full output buffer
                 float* __restrict__ repf,         // [8][1024]
                 float* __restrict__ repc,         // [8][1024]
                 int*   __restrict__ counter)      // last-block-done
{
    // 32 KB: B fragment planes, shared by 8 waves. Reused for loss flag.
    __shared__ __align__(16) unsigned char smem[32768];

    const int blk  = blockIdx.x;        // 1024: h = low 4 bits (bi-major)
    const int h    = blk & 15;
    const int grp  = blk >> 4;          // 64 groups x 128 tokens per head
    const int tid  = threadIdx.x;
    const int wave = __builtin_amdgcn_readfirstlane(tid >> 6);   // 0..7
    const int lane = tid & 63;
    const int col  = lane & 15;         // A-row (token low) == B-state low bits
    const int kg   = lane >> 4;
    const int tokb = grp * 128 + wave * 16;   // this wave's single tile

    // ---- stage B once per block: 32 KB linear copy, 512 threads x 4 x 16B ----
    {
        const char* wsrc = (const char*)wfrag + (size_t)h * 32768;
        #pragma unroll
        for (int i = 0; i < 4; ++i) {
            const int off = (i * 512 + tid) * 16;
            GLOAD_LDS16(wsrc + off, smem + off);
        }
    }

    const float b0 = bias[h * NSTATE +  0 + col];
    const float b1 = bias[h * NSTATE + 16 + col];
    const float b2 = bias[h * NSTATE + 32 + col];
    const float b3 = bias[h * NSTATE + 48 + col];

    __syncthreads();   // B planes ready

    const size_t srow = (size_t)(NHEAD * DDIM);
    const float* arow = x + (size_t)(tokb + col) * srow + h * DDIM + kg * 8;

    f32x4 acc[4];
    #pragma unroll
    for (int n = 0; n < 4; ++n) {
        f32x4 z = {0.f, 0.f, 0.f, 0.f};
        acc[n] = z;
    }

    // streamed A: 2 x f32x4 per ks (low reg demand; 8-way TLP hides latency)
    #pragma unroll
    for (int ks = 0; ks < 4; ++ks) {
        f32x4 g0 = *reinterpret_cast<const f32x4*>(arow + ks * 32);
        f32x4 g1 = *reinterpret_cast<const f32x4*>(arow + ks * 32 + 4);
        half8 ah, al;
        split8(g0, g1, ah, al);
        #pragma unroll
        for (int n = 0; n < 4; ++n) {   // chain order bit-identical R4-R18
            const int fo = (ks * 4 + n) * 2048 + lane * 16;
            half8 bh = *reinterpret_cast<const half8*>(smem + fo);
            half8 bl = *reinterpret_cast<const half8*>(smem + fo + 1024);
            acc[n] = __builtin_amdgcn_mfma_f32_16x16x32_f16(ah, bh, acc[n], 0, 0, 0);
            acc[n] = __builtin_amdgcn_mfma_f32_16x16x32_f16(ah, bl, acc[n], 0, 0, 0);
            acc[n] = __builtin_amdgcn_mfma_f32_16x16x32_f16(al, bh, acc[n], 0, 0, 0);
        }
    }

    // ---- epilogue (absmax-0-verified structure) ----
    float sc[4] = {0.f, 0.f, 0.f, 0.f};
    int   cn[4] = {0, 0, 0, 0};
    int   my_idx = 0;

    #pragma unroll
    for (int rg = 0; rg < 4; ++rg) {
        float L0 = acc[0][rg] + b0;
        float L1 = acc[1][rg] + b1;
        float L2 = acc[2][rg] + b2;
        float L3 = acc[3][rg] + b3;

        unsigned long long k0 = ((unsigned long long)ordf(L0) << 6) | (unsigned)(63 - ( 0 + col));
        unsigned long long k1 = ((unsigned long long)ordf(L1) << 6) | (unsigned)(63 - (16 + col));
        unsigned long long k2 = ((unsigned long long)ordf(L2) << 6) | (unsigned)(63 - (32 + col));
        unsigned long long k3 = ((unsigned long long)ordf(L3) << 6) | (unsigned)(63 - (48 + col));
        unsigned long long ka = k0 > k1 ? k0 : k1;
        unsigned long long kb = k2 > k3 ? k2 : k3;
        unsigned long long kk = ka > kb ? ka : kb;
        #pragma unroll
        for (int d = 1; d <= 8; d <<= 1) {
            unsigned long long o = __shfl_xor(kk, d);
            kk = kk > o ? kk : o;
        }
        const int idx = 63 - (int)(kk & 63ull);

        float e0 = __expf(L0), e1 = __expf(L1), e2 = __expf(L2), e3 = __expf(L3);
        float sm = (e0 + e1) + (e2 + e3);
        #pragma unroll
        for (int d = 1; d <= 8; d <<= 1) sm += __shfl_xor(sm, d);
        const float rinv = __builtin_amdgcn_rcpf(sm);
        sc[0] += e0 * rinv; sc[1] += e1 * rinv;
        sc[2] += e2 * rinv; sc[3] += e3 * rinv;

        cn[0] += (idx ==  0 + col);
        cn[1] += (idx == 16 + col);
        cn[2] += (idx == 32 + col);
        cn[3] += (idx == 48 + col);

        if (col == rg) my_idx = idx;    // owner lane captures its token
    }
    // direct idx store: 16 owner lanes, stride-64B dwords; same-line writes
    // from the 16 heads merge in the owning L2 slice. Fire-and-forget.
    if (col < 4)
        out[(size_t)TH + (size_t)(tokb + (kg << 2) + col) * NHEAD + h] = (float)my_idx;

    // wave reduce over kg groups -> replica atomics (contention-diluted)
    #pragma unroll
    for (int n = 0; n < 4; ++n) {
        sc[n] += __shfl_xor(sc[n], 16);
        sc[n] += __shfl_xor(sc[n], 32);
        cn[n] += __shfl_xor(cn[n], 16);
        cn[n] += __shfl_xor(cn[n], 32);
    }
    if (kg == 0) {
        const int rep = wave;           // 8 waves -> 8 replica slots
        #pragma unroll
        for (int n = 0; n < 4; ++n) {
            atomicAdd(repf + rep * 1024 + h * 64 + n * 16 + col, sc[n]);
            atomicAdd(repc + rep * 1024 + h * 64 + n * 16 + col, (float)cn[n]);
        }
        __threadfence();                // release this wave's ws updates
    }
    __syncthreads();

    // last-block-done: the 1024th arrival reduces rep and writes the loss
    volatile int* flag = (volatile int*)smem;
    if (tid == 0)
        *flag = (atomicAdd(counter, 1) == NBLK - 1) ? 1 : 0;
    __syncthreads();

    if (*flag) {
        __threadfence();                // acquire: all blocks' rep visible
        float part = 0.0f;
        #pragma unroll
        for (int k = 0; k < 2; ++k) {
            const int j = k * 512 + tid;
            float cf = 0.f, cc = 0.f;
            #pragma unroll
            for (int r = 0; r < 8; ++r) {
                cf += __hip_atomic_load(repf + r * 1024 + j, __ATOMIC_RELAXED,
                                        __HIP_MEMORY_SCOPE_AGENT);
                cc += __hip_atomic_load(repc + r * 1024 + j, __ATOMIC_RELAXED,
                                        __HIP_MEMORY_SCOPE_AGENT);
            }
            part += cf * cc;
        }
        #pragma unroll
        for (int d = 1; d <= 32; d <<= 1)
            part += __shfl_xor(part, d);
        float* redl = (float*)smem + 16;
        if (lane == 0) redl[wave] = part;
        __syncthreads();
        if (tid == 0) {
            float tot = 0.f;
            #pragma unroll
            for (int wv = 0; wv < 8; ++wv) tot += redl[wv];
            const float T = (float)TOKENS;
            out[2 * (size_t)TH] = tot * ((float)NSTATE / (T * T));
        }
    }
}

extern "C" void kernel_launch(void* const* d_in, const int* in_sizes, int n_in,
                              void* d_out, int out_size, void* d_ws, size_t ws_size,
                              hipStream_t stream)
{
    const float* x    = (const float*)d_in[0];
    const float* w    = (const float*)d_in[1];
    const float* bias = (const float*)d_in[2];
    float* out = (float*)d_out;

    half8* wfrag   = (half8*)d_ws;
    float* rep     = (float*)((char*)d_ws + REP_OFF);
    float* repf    = rep;
    float* repc    = rep + 8192;
    int*   counter = (int*)((char*)d_ws + CNT_OFF);

    prep_w<<<dim3(64), dim3(256), 0, stream>>>(w, wfrag, rep, counter, out);
    router_mfma<<<dim3(NBLK), dim3(512), 0, stream>>>(x, wfrag, bias, out,
                                                      repf, repc, counter);
}

// Round 20
// 28.785 us; speedup vs baseline: 6.7607x; 6.7607x over previous
//
#include <hip/hip_runtime.h>

// MultiHeadRouter: B=2, L=4096, H=16, S=64, D=128
// out (float32): [T*H ones][T*H argmax-as-float][1 loss], T = 8192
//
// R20 = R18 (best: 28.87us, absmax 0) + two safe micro-deltas:
// - prep_w over 256x64 blocks (same t-mapping; one wave/CU) + ones-plane fill
//   (coalesced f32x4, R19-verified path) + rep zero.
// - finale: idx transpose + loss only (ones already written by prep_w).
// Router bit-identical to R15/R18 (absmax 0 x3). NO device-scope fences
// (R19: per-block __threadfence = 200us pathology), NO scattered out stores
// (R19: 16x write amplification).

#define TOKENS  8192
#define NHEAD   16
#define NSTATE  64
#define DDIM    128
#define TH      (TOKENS * NHEAD)

// d_ws layout
#define WFRAG_BYTES (1u << 19)                 // 512 KB fragment planes
#define REP_OFF     WFRAG_BYTES                // 64 KB: repf[8][1024], repc[8][1024]
#define REP_BYTES   65536
#define IDX_OFF     (WFRAG_BYTES + REP_BYTES)  // 512 KB idx_scr[16][8192]

typedef _Float16 half8 __attribute__((ext_vector_type(8)));
typedef float    f32x4 __attribute__((ext_vector_type(4)));

#define GLOAD_LDS16(gsrc, ldst)                                           \
    __builtin_amdgcn_global_load_lds(                                     \
        (const __attribute__((address_space(1))) void*)(gsrc),            \
        (__attribute__((address_space(3))) void*)(ldst), 16, 0, 0)

__device__ __forceinline__ unsigned int ordf(float f) {
    unsigned int u = __float_as_uint(f);
    return (u & 0x80000000u) ? ~u : (u | 0x80000000u);   // order-preserving
}

__device__ __forceinline__ void split8(const f32x4 v0, const f32x4 v1,
                                       half8& hh, half8& ll) {
    #pragma unroll
    for (int j = 0; j < 4; ++j) {
        _Float16 h0 = (_Float16)v0[j];
        hh[j]     = h0;  ll[j]     = (_Float16)(v0[j] - (float)h0);
        _Float16 h1 = (_Float16)v1[j];
        hh[4 + j] = h1;  ll[4 + j] = (_Float16)(v1[j] - (float)h1);
    }
}

// One-shot: W -> fragment-ordered f16 hi/lo planes (R7-verified layout),
// zero replicas, fill the ones output plane. 256 blocks x 64 threads
// (same t mapping as the verified 64x256 version; spreads across all CUs).
__global__ __launch_bounds__(64)
void prep_w(const float* __restrict__ w, half8* __restrict__ wfrag,
            float* __restrict__ rep, float* __restrict__ out)
{
    const int t    = blockIdx.x * 64 + threadIdx.x;    // 16384 threads
    rep[t] = 0.0f;

    // ones plane: 131072 floats, 8 per thread, contiguous (R19-verified)
    {
        const f32x4 one4 = {1.f, 1.f, 1.f, 1.f};
        f32x4* op = reinterpret_cast<f32x4*>(out) + (size_t)t * 2;
        op[0] = one4; op[1] = one4;
    }

    const int lane = t & 63;
    const int n    = (t >> 6) & 3;
    const int ks   = (t >> 8) & 3;
    const int h    = t >> 10;
    const int s    = n * 16 + (lane & 15);
    const int k0   = ks * 32 + (lane >> 4) * 8;
    const float* src = w + (size_t)(h * NSTATE + s) * DDIM + k0;
    f32x4 v0 = *reinterpret_cast<const f32x4*>(src);
    f32x4 v1 = *reinterpret_cast<const f32x4*>(src + 4);
    half8 hv, lv;
    split8(v0, v1, hv, lv);
    const size_t hb = (size_t)h * 2048;
    const int fb = (ks * 4 + n) * 2;
    wfrag[hb + (size_t)fb * 64 + lane]       = hv;
    wfrag[hb + (size_t)(fb + 1) * 64 + lane] = lv;
}

__global__ __launch_bounds__(512)
void router_mfma(const float* __restrict__ x,      // [T,H,D]
                 const half8* __restrict__ wfrag,  // fragment planes
                 const float* __restrict__ bias,   // [H,S]
                 float* __restrict__ idx_scr,      // [H][T] h-major idx
                 float* __restrict__ repf,         // [8][1024]
                 float* __restrict__ repc)         // [8][1024]
{
    // 32 KB: B fragment planes, shared by 8 waves.
    __shared__ __align__(16) unsigned char smem[32768];

    const int blk  = blockIdx.x;        // 1024: h = low 4 bits (bi-major)
    const int h    = blk & 15;
    const int grp  = blk >> 4;          // 64 groups x 128 tokens per head
    const int tid  = threadIdx.x;
    const int wave = __builtin_amdgcn_readfirstlane(tid >> 6);   // 0..7
    const int lane = tid & 63;
    const int col  = lane & 15;         // A-row (token low) == B-state low bits
    const int kg   = lane >> 4;
    const int tokb = grp * 128 + wave * 16;   // this wave's single tile

    // ---- stage B once per block: 32 KB linear copy, 512 threads x 4 x 16B ----
    {
        const char* wsrc = (const char*)wfrag + (size_t)h * 32768;
        #pragma unroll
        for (int i = 0; i < 4; ++i) {
            const int off = (i * 512 + tid) * 16;
            GLOAD_LDS16(wsrc + off, smem + off);
        }
    }

    const float b0 = bias[h * NSTATE +  0 + col];
    const float b1 = bias[h * NSTATE + 16 + col];
    const float b2 = bias[h * NSTATE + 32 + col];
    const float b3 = bias[h * NSTATE + 48 + col];

    __syncthreads();   // the only barrier: B planes ready

    const size_t srow = (size_t)(NHEAD * DDIM);
    const float* arow = x + (size_t)(tokb + col) * srow + h * DDIM + kg * 8;

    f32x4 acc[4];
    #pragma unroll
    for (int n = 0; n < 4; ++n) {
        f32x4 z = {0.f, 0.f, 0.f, 0.f};
        acc[n] = z;
    }

    // streamed A: 2 x f32x4 per ks (low reg demand; 8-way TLP hides latency)
    #pragma unroll
    for (int ks = 0; ks < 4; ++ks) {
        f32x4 g0 = *reinterpret_cast<const f32x4*>(arow + ks * 32);
        f32x4 g1 = *reinterpret_cast<const f32x4*>(arow + ks * 32 + 4);
        half8 ah, al;
        split8(g0, g1, ah, al);
        #pragma unroll
        for (int n = 0; n < 4; ++n) {   // chain order bit-identical R4-R18
            const int fo = (ks * 4 + n) * 2048 + lane * 16;
            half8 bh = *reinterpret_cast<const half8*>(smem + fo);
            half8 bl = *reinterpret_cast<const half8*>(smem + fo + 1024);
            acc[n] = __builtin_amdgcn_mfma_f32_16x16x32_f16(ah, bh, acc[n], 0, 0, 0);
            acc[n] = __builtin_amdgcn_mfma_f32_16x16x32_f16(ah, bl, acc[n], 0, 0, 0);
            acc[n] = __builtin_amdgcn_mfma_f32_16x16x32_f16(al, bh, acc[n], 0, 0, 0);
        }
    }

    // ---- epilogue (absmax-0-verified structure) ----
    float sc[4] = {0.f, 0.f, 0.f, 0.f};
    int   cn[4] = {0, 0, 0, 0};
    int   my_idx = 0;

    #pragma unroll
    for (int rg = 0; rg < 4; ++rg) {
        float L0 = acc[0][rg] + b0;
        float L1 = acc[1][rg] + b1;
        float L2 = acc[2][rg] + b2;
        float L3 = acc[3][rg] + b3;

        unsigned long long k0 = ((unsigned long long)ordf(L0) << 6) | (unsigned)(63 - ( 0 + col));
        unsigned long long k1 = ((unsigned long long)ordf(L1) << 6) | (unsigned)(63 - (16 + col));
        unsigned long long k2 = ((unsigned long long)ordf(L2) << 6) | (unsigned)(63 - (32 + col));
        unsigned long long k3 = ((unsigned long long)ordf(L3) << 6) | (unsigned)(63 - (48 + col));
        unsigned long long ka = k0 > k1 ? k0 : k1;
        unsigned long long kb = k2 > k3 ? k2 : k3;
        unsigned long long kk = ka > kb ? ka : kb;
        #pragma unroll
        for (int d = 1; d <= 8; d <<= 1) {
            unsigned long long o = __shfl_xor(kk, d);
            kk = kk > o ? kk : o;
        }
        const int idx = 63 - (int)(kk & 63ull);

        float e0 = __expf(L0), e1 = __expf(L1), e2 = __expf(L2), e3 = __expf(L3);
        float sm = (e0 + e1) + (e2 + e3);
        #pragma unroll
        for (int d = 1; d <= 8; d <<= 1) sm += __shfl_xor(sm, d);
        const float rinv = __builtin_amdgcn_rcpf(sm);
        sc[0] += e0 * rinv; sc[1] += e1 * rinv;
        sc[2] += e2 * rinv; sc[3] += e3 * rinv;

        cn[0] += (idx ==  0 + col);
        cn[1] += (idx == 16 + col);
        cn[2] += (idx == 32 + col);
        cn[3] += (idx == 48 + col);

        if (col == rg) my_idx = idx;    // owner lane captures its token
    }
    // 16 owner lanes (col<4) -> 64 contiguous bytes
    if (col < 4)
        idx_scr[(size_t)h * TOKENS + tokb + (kg << 2) + col] = (float)my_idx;

    // wave reduce over kg groups -> replica atomics (contention-diluted)
    #pragma unroll
    for (int n = 0; n < 4; ++n) {
        sc[n] += __shfl_xor(sc[n], 16);
        sc[n] += __shfl_xor(sc[n], 32);
        cn[n] += __shfl_xor(cn[n], 16);
        cn[n] += __shfl_xor(cn[n], 32);
    }
    if (kg == 0) {
        const int rep = ((blk << 3) | wave) & 7;
        #pragma unroll
        for (int n = 0; n < 4; ++n) {
            atomicAdd(repf + rep * 1024 + h * 64 + n * 16 + col, sc[n]);
            atomicAdd(repc + rep * 1024 + h * 64 + n * 16 + col, (float)cn[n]);
        }
    }
}

// finale: 257 blocks. b<256: transpose 32 tokens x 16 heads via padded LDS
// (idx plane only; ones already written by prep_w); b==256: loss.
__global__ __launch_bounds__(256)
void finale(const float* __restrict__ idx_scr,
            const float* __restrict__ repf,
            const float* __restrict__ repc,
            float* __restrict__ out)
{
    const int b   = blockIdx.x;
    const int tid = threadIdx.x;

    if (b < 256) {
        __shared__ float tl[32][17];
        const int tk = tid & 31, hh = tid >> 5;   // hh 0..7 (+8 second pass)
        #pragma unroll
        for (int i = 0; i < 2; ++i)
            tl[tk][i * 8 + hh] = idx_scr[(size_t)(i * 8 + hh) * TOKENS + b * 32 + tk];
        __syncthreads();
        #pragma unroll
        for (int i = 0; i < 2; ++i) {
            const int o = i * 256 + tid;          // 512 outputs: [32 tok][16 heads]
            out[(size_t)TH + (size_t)b * 512 + o] = tl[o >> 4][o & 15];
        }
    } else {
        float part = 0.0f;
        for (int j = tid; j < NHEAD * NSTATE; j += 256) {
            float cf = 0.f, cc = 0.f;
            #pragma unroll
            for (int r = 0; r < 8; ++r) {
                cf += repf[r * 1024 + j];
                cc += repc[r * 1024 + j];
            }
            part += cf * cc;
        }
        #pragma unroll
        for (int d = 1; d <= 32; d <<= 1)
            part += __shfl_xor(part, d);
        __shared__ float red[4];
        const int wv = tid >> 6, lane = tid & 63;
        if (lane == 0) red[wv] = part;
        __syncthreads();
        if (tid == 0) {
            const float tot = red[0] + red[1] + red[2] + red[3];
            const float T = (float)TOKENS;
            out[2 * (size_t)TH] = tot * ((float)NSTATE / (T * T));
        }
    }
}

extern "C" void kernel_launch(void* const* d_in, const int* in_sizes, int n_in,
                              void* d_out, int out_size, void* d_ws, size_t ws_size,
                              hipStream_t stream)
{
    const float* x    = (const float*)d_in[0];
    const float* w    = (const float*)d_in[1];
    const float* bias = (const float*)d_in[2];
    float* out = (float*)d_out;

    half8* wfrag   = (half8*)d_ws;
    float* rep     = (float*)((char*)d_ws + REP_OFF);
    float* repf    = rep;
    float* repc    = rep + 8192;
    float* idx_scr = (float*)((char*)d_ws + IDX_OFF);

    prep_w<<<dim3(256), dim3(64), 0, stream>>>(w, wfrag, rep, out);
    router_mfma<<<dim3(1024), dim3(512), 0, stream>>>(x, wfrag, bias,
                                                      idx_scr, repf, repc);
    finale<<<dim3(257), dim3(256), 0, stream>>>(idx_scr, repf, repc, out);
}